// Round 1
// baseline (4809.932 us; speedup 1.0000x reference)
//
#include <hip/hip_runtime.h>
#include <hip/hip_bf16.h>

#define BB 8
#define TT 4096
#define NHH 16
#define MDD 64
#define FFF 256
#define HEADSS 4
#define DHH 16
#define PEHH 32

static __device__ __forceinline__ float lrelu(float x) { return x > 0.0f ? x : 0.2f * x; }
static __device__ __forceinline__ unsigned long long umin64(unsigned long long a, unsigned long long b) {
    return a < b ? a : b;
}

// ---------------- Kernel 1: 16-NN search per token (batch-independent) ----------------
__global__ __launch_bounds__(256) void k_neighbors(const float* __restrict__ c1,
                                                   const float* __restrict__ c2,
                                                   int* __restrict__ idx,
                                                   float* __restrict__ c1n,
                                                   float* __restrict__ c2n) {
    int t = blockIdx.x;
    int tid = threadIdx.x;
    __shared__ unsigned long long keys[TT];   // 32 KB
    __shared__ unsigned long long red[256];
    float c1t = c1[t], c2t = c2[t];
    for (int j = tid; j < TT; j += 256) {
        // match numpy exactly: no FMA contraction
        float d1 = __fsub_rn(c1[j], c1t);
        float d2 = __fsub_rn(c2[j], c2t);
        float dist = __fadd_rn(__fmul_rn(d1, d1), __fmul_rn(d2, d2));
        unsigned long long db = (unsigned long long)__float_as_uint(dist);
        keys[j] = (db << 32) | (unsigned int)j;   // ties -> lower index (top_k stable)
    }
    __syncthreads();
    for (int s = 0; s < NHH; ++s) {
        unsigned long long m = ~0ull;
        for (int j = tid; j < TT; j += 256) m = umin64(m, keys[j]);
        red[tid] = m;
        __syncthreads();
        for (int off = 128; off > 0; off >>= 1) {
            if (tid < off) red[tid] = umin64(red[tid], red[tid + off]);
            __syncthreads();
        }
        unsigned long long kmin = red[0];
        // remove selected (key unique since it embeds the index)
        for (int j = tid; j < TT; j += 256)
            if (keys[j] == kmin) keys[j] = ~0ull;
        if (tid == 0) {
            int jj = (int)(unsigned int)(kmin & 0xffffffffu);
            idx[t * NHH + s] = jj;
            c1n[t * NHH + s] = __fsub_rn(c1[jj], c1t);
            c2n[t * NHH + s] = __fsub_rn(c2[jj], c2t);
        }
        __syncthreads();
    }
}

// ---------------- Kernel 2: relative-position bias MLP ----------------
__global__ __launch_bounds__(256) void k_bias(const float* __restrict__ c1n,
                                              const float* __restrict__ c2n,
                                              const float* __restrict__ Wp1,
                                              const float* __restrict__ bp1,
                                              const float* __restrict__ Wp2,
                                              const float* __restrict__ bp2,
                                              float* __restrict__ bias) {
    __shared__ float sWp1[2 * PEHH], sbp1[PEHH], sWp2[PEHH * HEADSS], sbp2[HEADSS];
    int tid = threadIdx.x;
    if (tid < 2 * PEHH) sWp1[tid] = Wp1[tid];
    if (tid < PEHH) sbp1[tid] = bp1[tid];
    if (tid < PEHH * HEADSS) sWp2[tid] = Wp2[tid];
    if (tid < HEADSS) sbp2[tid] = bp2[tid];
    __syncthreads();
    int g = blockIdx.x * 256 + tid;            // T*NH*NH = 1,048,576
    if (g >= TT * NHH * NHH) return;
    int j = g & 15, i = (g >> 4) & 15, t = g >> 8;
    float p1 = c1n[t * NHH + i] - c1n[t * NHH + j];
    float p2 = c2n[t * NHH + i] - c2n[t * NHH + j];
    float acc0 = sbp2[0], acc1 = sbp2[1], acc2 = sbp2[2], acc3 = sbp2[3];
    #pragma unroll
    for (int kk = 0; kk < PEHH; ++kk) {
        float h = lrelu(p1 * sWp1[kk] + p2 * sWp1[PEHH + kk] + sbp1[kk]);
        acc0 += h * sWp2[kk * HEADSS + 0];
        acc1 += h * sWp2[kk * HEADSS + 1];
        acc2 += h * sWp2[kk * HEADSS + 2];
        acc3 += h * sWp2[kk * HEADSS + 3];
    }
    float* bt = bias + (size_t)t * HEADSS * NHH * NHH;
    bt[(0 * NHH + i) * NHH + j] = acc0;
    bt[(1 * NHH + i) * NHH + j] = acc1;
    bt[(2 * NHH + i) * NHH + j] = acc2;
    bt[(3 * NHH + i) * NHH + j] = acc3;
}

// ---------------- Kernel 3: LayerNorm 1 (per (b,t) over 64) ----------------
__global__ __launch_bounds__(256) void k_ln1(const float* __restrict__ x,
                                             const float* __restrict__ g1,
                                             const float* __restrict__ be1,
                                             float* __restrict__ xn) {
    int row = blockIdx.x * 4 + (threadIdx.x >> 6);
    int lane = threadIdx.x & 63;
    float v = x[(size_t)row * MDD + lane];
    float s = v;
    for (int off = 32; off > 0; off >>= 1) s += __shfl_down(s, off);
    s = __shfl(s, 0);
    float m = s * (1.0f / 64.0f);
    float d = v - m;
    float sq = d * d;
    for (int off = 32; off > 0; off >>= 1) sq += __shfl_down(sq, off);
    sq = __shfl(sq, 0);
    float var = sq * (1.0f / 64.0f);
    float inv = 1.0f / sqrtf(var + 1e-5f);
    xn[(size_t)row * MDD + lane] = d * inv * g1[lane] + be1[lane];
}

// ---------------- Kernel 4: per-(b,t) attention + FF block, outputs xu row ----------------
__global__ __launch_bounds__(256) void k_main(const float* __restrict__ xn,
                                              const int* __restrict__ idx,
                                              const float* __restrict__ bias,
                                              const float* __restrict__ Wq, const float* __restrict__ bq,
                                              const float* __restrict__ Wk, const float* __restrict__ bk,
                                              const float* __restrict__ Wv, const float* __restrict__ bv,
                                              const float* __restrict__ ls,
                                              const float* __restrict__ Wo, const float* __restrict__ bo,
                                              const float* __restrict__ g2, const float* __restrict__ be2,
                                              const float* __restrict__ Wn1, const float* __restrict__ bn1,
                                              const float* __restrict__ Wn2, const float* __restrict__ bn2,
                                              const float* __restrict__ g3, const float* __restrict__ be3,
                                              float* __restrict__ xu) {
    int n = blockIdx.x;            // b*T + t
    int b = n >> 12;
    int t = n & (TT - 1);
    int tid = threadIdx.x;

    __shared__ float xg[NHH][MDD];     // gathered xn (residual base)
    __shared__ float qs[NHH][MDD];     // q, later concat(av)
    __shared__ float ksm[NHH][MDD];    // k, later xf
    __shared__ float vs[NHH][MDD];     // v, later xfn/xf2
    __shared__ float att[HEADSS][NHH][NHH];
    __shared__ float hbuf[NHH][FFF];   // 16 KB
    __shared__ float red[256], red2[256];
    __shared__ int sidx[NHH];
    __shared__ float rowm[NHH], rowinv[NHH], rows[NHH];

    if (tid < NHH) sidx[tid] = idx[t * NHH + tid];
    __syncthreads();
    // gather neighbors
    for (int o = tid; o < NHH * MDD; o += 256) {
        int r = o >> 6, c = o & 63;
        xg[r][c] = xn[((size_t)b * TT + sidx[r]) * MDD + c];
    }
    __syncthreads();
    // QKV projections: thread owns column c for 4 rows
    {
        int c = tid & 63, r0 = tid >> 6;     // r0 in 0..3; rows r0, r0+4, r0+8, r0+12
        float aq[4], ak[4], av[4];
        #pragma unroll
        for (int u = 0; u < 4; ++u) { aq[u] = bq[c]; ak[u] = bk[c]; av[u] = bv[c]; }
        for (int kk = 0; kk < MDD; ++kk) {
            float wq = Wq[kk * MDD + c], wk = Wk[kk * MDD + c], wv = Wv[kk * MDD + c];
            #pragma unroll
            for (int u = 0; u < 4; ++u) {
                float xv = xg[r0 + 4 * u][kk];
                aq[u] += xv * wq; ak[u] += xv * wk; av[u] += xv * wv;
            }
        }
        #pragma unroll
        for (int u = 0; u < 4; ++u) {
            qs[r0 + 4 * u][c] = aq[u]; ksm[r0 + 4 * u][c] = ak[u]; vs[r0 + 4 * u][c] = av[u];
        }
    }
    __syncthreads();
    // L2-normalize q,k per (row, head)
    if (tid < NHH * HEADSS) {
        int r = tid >> 2, h = tid & 3;
        float sq = 0.0f, sk = 0.0f;
        #pragma unroll
        for (int d = 0; d < DHH; ++d) {
            float qv = qs[r][h * DHH + d]; sq += qv * qv;
            float kv = ksm[r][h * DHH + d]; sk += kv * kv;
        }
        float iq = 1.0f / fmaxf(sqrtf(sq), 1e-6f);
        float ik = 1.0f / fmaxf(sqrtf(sk), 1e-6f);
        #pragma unroll
        for (int d = 0; d < DHH; ++d) {
            qs[r][h * DHH + d] *= iq;
            ksm[r][h * DHH + d] *= ik;
        }
    }
    __syncthreads();
    // attention scores + bias
    for (int o = tid; o < HEADSS * NHH * NHH; o += 256) {
        int j = o & 15, i = (o >> 4) & 15, h = o >> 8;
        float s = 0.0f;
        #pragma unroll
        for (int d = 0; d < DHH; ++d) s += qs[i][h * DHH + d] * ksm[j][h * DHH + d];
        float scale = expf(fminf(ls[h], 4.60517018598809136804f));   // log(100)
        s = s * scale + bias[(((size_t)t * HEADSS + h) * NHH + i) * NHH + j];
        att[h][i][j] = s;
    }
    __syncthreads();
    // softmax over j
    if (tid < HEADSS * NHH) {
        int h = tid >> 4, i = tid & 15;
        float mx = att[h][i][0];
        #pragma unroll
        for (int j = 1; j < NHH; ++j) mx = fmaxf(mx, att[h][i][j]);
        float sm = 0.0f;
        #pragma unroll
        for (int j = 0; j < NHH; ++j) { float e = expf(att[h][i][j] - mx); att[h][i][j] = e; sm += e; }
        float inv = 1.0f / sm;
        #pragma unroll
        for (int j = 0; j < NHH; ++j) att[h][i][j] *= inv;
    }
    __syncthreads();
    // av (concat heads) -> qs
    for (int o = tid; o < NHH * MDD; o += 256) {
        int r = o >> 6, c = o & 63;
        int h = c >> 4;
        float s = 0.0f;
        #pragma unroll
        for (int j = 0; j < NHH; ++j) s += att[h][r][j] * vs[j][c];
        qs[r][c] = s;
    }
    __syncthreads();
    // out-proj + residual -> ksm (xf)
    {
        int c = tid & 63, r0 = tid >> 6;
        float a[4];
        #pragma unroll
        for (int u = 0; u < 4; ++u) a[u] = bo[c];
        for (int kk = 0; kk < MDD; ++kk) {
            float w = Wo[kk * MDD + c];
            #pragma unroll
            for (int u = 0; u < 4; ++u) a[u] += qs[r0 + 4 * u][kk] * w;
        }
        __syncthreads();   // qs reads done before overwriting? (we don't overwrite qs; sync for ksm write below)
        #pragma unroll
        for (int u = 0; u < 4; ++u) ksm[r0 + 4 * u][c] = xg[r0 + 4 * u][c] + a[u];
    }
    __syncthreads();
    // LN2 per row -> vs (xfn)
    {
        int r = tid >> 4, s4 = tid & 15;
        float ps = 0.0f, pq = 0.0f;
        #pragma unroll
        for (int u = 0; u < 4; ++u) { float v = ksm[r][s4 * 4 + u]; ps += v; pq += v * v; }
        red[tid] = ps; red2[tid] = pq;
    }
    __syncthreads();
    if (tid < NHH) {
        float s = 0.0f, q = 0.0f;
        #pragma unroll
        for (int u = 0; u < 16; ++u) { s += red[tid * 16 + u]; q += red2[tid * 16 + u]; }
        float m = s * (1.0f / 64.0f);
        float var = q * (1.0f / 64.0f) - m * m;
        rowm[tid] = m;
        rowinv[tid] = 1.0f / sqrtf(var + 1e-5f);
    }
    __syncthreads();
    for (int o = tid; o < NHH * MDD; o += 256) {
        int r = o >> 6, c = o & 63;
        vs[r][c] = (ksm[r][c] - rowm[r]) * rowinv[r] * g2[c] + be2[c];
    }
    __syncthreads();
    // FF layer 1: hbuf[r][j] = lrelu(vs[r,:] @ Wn1[:,j] + bn1[j]); thread owns column j = tid
    {
        int j = tid;
        float a[NHH];
        #pragma unroll
        for (int r = 0; r < NHH; ++r) a[r] = bn1[j];
        for (int kk = 0; kk < MDD; ++kk) {
            float w = Wn1[kk * FFF + j];
            #pragma unroll
            for (int r = 0; r < NHH; ++r) a[r] += vs[r][kk] * w;
        }
        #pragma unroll
        for (int r = 0; r < NHH; ++r) hbuf[r][j] = lrelu(a[r]);
    }
    __syncthreads();
    // FF layer 2 (256 -> 1) per row
    {
        int r = tid >> 4, s4 = tid & 15;
        float a = 0.0f;
        #pragma unroll
        for (int u = 0; u < 16; ++u) a += hbuf[r][s4 * 16 + u] * Wn2[s4 * 16 + u];
        red[tid] = a;
    }
    __syncthreads();
    if (tid < NHH) {
        float a = bn2[0];
        #pragma unroll
        for (int u = 0; u < 16; ++u) a += red[tid * 16 + u];
        rows[tid] = lrelu(a);
    }
    __syncthreads();
    // residual add + LN3 over flat 1024 -> xu
    {
        float ps = 0.0f, pq = 0.0f;
        #pragma unroll
        for (int u = 0; u < 4; ++u) {
            int o = tid * 4 + u;
            int r = o >> 6, c = o & 63;
            float v = vs[r][c] + rows[r];
            vs[r][c] = v;
            ps += v; pq += v * v;
        }
        red[tid] = ps; red2[tid] = pq;
    }
    __syncthreads();
    for (int off = 128; off > 0; off >>= 1) {
        if (tid < off) { red[tid] += red[tid + off]; red2[tid] += red2[tid + off]; }
        __syncthreads();
    }
    float m = red[0] * (1.0f / 1024.0f);
    float var = red2[0] * (1.0f / 1024.0f) - m * m;
    float inv = 1.0f / sqrtf(var + 1e-5f);
    #pragma unroll
    for (int u = 0; u < 4; ++u) {
        int o = tid * 4 + u;
        int r = o >> 6, c = o & 63;
        xu[(size_t)n * 1024 + o] = (vs[r][c] - m) * inv * g3[o] + be3[o];
    }
}

// ---------------- Kernel 5: fused final GEMM (xu @ Wu1 -> lrelu -> @ Wu2 -> lrelu) ----------------
__global__ __launch_bounds__(256) void k_final(const float* __restrict__ xu,
                                               const float* __restrict__ Wu1,
                                               const float* __restrict__ bu1,
                                               const float* __restrict__ Wu2,
                                               const float* __restrict__ bu2,
                                               float* __restrict__ out) {
    int tile = blockIdx.x;           // 16 rows per block
    int tid = threadIdx.x;
    int r = tid >> 4, s = tid & 15;
    __shared__ float xus[NHH * 1024];   // 64 KB
    __shared__ float red[256];
    for (int o = tid; o < 16 * 1024; o += 256)
        xus[o] = xu[(size_t)tile * 16 * 1024 + o];
    __syncthreads();
    float acc[16][4];
    #pragma unroll
    for (int g = 0; g < 16; ++g) {
        int j0 = g * 64 + s * 4;
        acc[g][0] = bu1[j0]; acc[g][1] = bu1[j0 + 1]; acc[g][2] = bu1[j0 + 2]; acc[g][3] = bu1[j0 + 3];
    }
    const float* xrow = &xus[r * 1024];
    for (int kc = 0; kc < 1024; kc += 8) {
        float xr[8];
        #pragma unroll
        for (int u = 0; u < 8; ++u) xr[u] = xrow[kc + u];
        #pragma unroll
        for (int g = 0; g < 16; ++g) {
            int j0 = g * 64 + s * 4;
            #pragma unroll
            for (int u = 0; u < 8; ++u) {
                float4 w = *reinterpret_cast<const float4*>(&Wu1[(size_t)(kc + u) * 1024 + j0]);
                acc[g][0] += xr[u] * w.x;
                acc[g][1] += xr[u] * w.y;
                acc[g][2] += xr[u] * w.z;
                acc[g][3] += xr[u] * w.w;
            }
        }
    }
    float accout = 0.0f;
    #pragma unroll
    for (int g = 0; g < 16; ++g) {
        int j0 = g * 64 + s * 4;
        #pragma unroll
        for (int u = 0; u < 4; ++u) accout += lrelu(acc[g][u]) * Wu2[j0 + u];
    }
    red[tid] = accout;
    __syncthreads();
    if (s == 0) {
        float a = bu2[0];
        #pragma unroll
        for (int u = 0; u < 16; ++u) a += red[r * 16 + u];
        out[tile * 16 + r] = lrelu(a);
    }
}

extern "C" void kernel_launch(void* const* d_in, const int* in_sizes, int n_in,
                              void* d_out, int out_size, void* d_ws, size_t ws_size,
                              hipStream_t stream) {
    const float* x   = (const float*)d_in[0];
    const float* c1  = (const float*)d_in[1];
    const float* c2  = (const float*)d_in[2];
    const float* g1  = (const float*)d_in[3];
    const float* be1 = (const float*)d_in[4];
    const float* Wq  = (const float*)d_in[5];
    const float* bq  = (const float*)d_in[6];
    const float* Wk  = (const float*)d_in[7];
    const float* bk  = (const float*)d_in[8];
    const float* Wv  = (const float*)d_in[9];
    const float* bv  = (const float*)d_in[10];
    const float* ls  = (const float*)d_in[11];
    const float* Wo  = (const float*)d_in[12];
    const float* bo  = (const float*)d_in[13];
    const float* Wp1 = (const float*)d_in[14];
    const float* bp1 = (const float*)d_in[15];
    const float* Wp2 = (const float*)d_in[16];
    const float* bp2 = (const float*)d_in[17];
    const float* g2  = (const float*)d_in[18];
    const float* be2 = (const float*)d_in[19];
    const float* Wn1 = (const float*)d_in[20];
    const float* bn1 = (const float*)d_in[21];
    const float* Wn2 = (const float*)d_in[22];
    const float* bn2 = (const float*)d_in[23];
    const float* g3  = (const float*)d_in[24];
    const float* be3 = (const float*)d_in[25];
    const float* Wu1 = (const float*)d_in[26];
    const float* bu1 = (const float*)d_in[27];
    const float* Wu2 = (const float*)d_in[28];
    const float* bu2 = (const float*)d_in[29];
    float* out = (float*)d_out;

    char* ws = (char*)d_ws;
    size_t off = 0;
    int*   idx  = (int*)(ws + off);   off += (size_t)TT * NHH * 4;          // 256 KB
    float* c1n  = (float*)(ws + off); off += (size_t)TT * NHH * 4;          // 256 KB
    float* c2n  = (float*)(ws + off); off += (size_t)TT * NHH * 4;          // 256 KB
    float* bias = (float*)(ws + off); off += (size_t)TT * HEADSS * NHH * NHH * 4;  // 16 MB
    float* xn   = (float*)(ws + off); off += (size_t)BB * TT * MDD * 4;     // 8 MB
    float* xuB  = (float*)(ws + off); off += (size_t)BB * TT * NHH * MDD * 4;  // 134 MB

    k_neighbors<<<TT, 256, 0, stream>>>(c1, c2, idx, c1n, c2n);
    k_bias<<<(TT * NHH * NHH + 255) / 256, 256, 0, stream>>>(c1n, c2n, Wp1, bp1, Wp2, bp2, bias);
    k_ln1<<<(BB * TT) / 4, 256, 0, stream>>>(x, g1, be1, xn);
    k_main<<<BB * TT, 256, 0, stream>>>(xn, idx, bias, Wq, bq, Wk, bk, Wv, bv, ls, Wo, bo,
                                        g2, be2, Wn1, bn1, Wn2, bn2, g3, be3, xuB);
    k_final<<<(BB * TT) / 16, 256, 0, stream>>>(xuB, Wu1, bu1, Wu2, bu2, out);
}

// Round 2
// 1242.325 us; speedup vs baseline: 3.8717x; 3.8717x over previous
//
#include <hip/hip_runtime.h>
#include <hip/hip_bf16.h>

#define BB 8
#define TT 4096
#define NHH 16
#define MDD 64
#define FFF 256
#define HEADSS 4
#define DHH 16
#define PEHH 32

#define GM (BB * TT)      // 32768
#define GK 1024
#define GN 1024
#define BMt 128
#define BNt 128
#define BKt 64
#define NCHUNK (GN / BNt) // 8

typedef float f32x4 __attribute__((ext_vector_type(4)));
typedef short bf16x8 __attribute__((ext_vector_type(8)));

static __device__ __forceinline__ float lrelu(float x) { return x > 0.0f ? x : 0.2f * x; }
static __device__ __forceinline__ unsigned long long umin64(unsigned long long a, unsigned long long b) {
    return a < b ? a : b;
}
static __device__ __forceinline__ unsigned short f2bf(float f) {
    unsigned u = __float_as_uint(f);
    u = u + 0x7fffu + ((u >> 16) & 1u);   // RNE
    return (unsigned short)(u >> 16);
}

// ---------------- Kernel 1: 16-NN search per token (batch-independent) ----------------
__global__ __launch_bounds__(256) void k_neighbors(const float* __restrict__ c1,
                                                   const float* __restrict__ c2,
                                                   int* __restrict__ idx,
                                                   float* __restrict__ c1n,
                                                   float* __restrict__ c2n) {
    int t = blockIdx.x;
    int tid = threadIdx.x;
    __shared__ unsigned long long keys[TT];   // 32 KB
    __shared__ unsigned long long red[256];
    float c1t = c1[t], c2t = c2[t];
    for (int j = tid; j < TT; j += 256) {
        float d1 = __fsub_rn(c1[j], c1t);
        float d2 = __fsub_rn(c2[j], c2t);
        float dist = __fadd_rn(__fmul_rn(d1, d1), __fmul_rn(d2, d2));
        unsigned long long db = (unsigned long long)__float_as_uint(dist);
        keys[j] = (db << 32) | (unsigned int)j;   // ties -> lower index (top_k stable)
    }
    __syncthreads();
    for (int s = 0; s < NHH; ++s) {
        unsigned long long m = ~0ull;
        for (int j = tid; j < TT; j += 256) m = umin64(m, keys[j]);
        red[tid] = m;
        __syncthreads();
        for (int off = 128; off > 0; off >>= 1) {
            if (tid < off) red[tid] = umin64(red[tid], red[tid + off]);
            __syncthreads();
        }
        unsigned long long kmin = red[0];
        for (int j = tid; j < TT; j += 256)
            if (keys[j] == kmin) keys[j] = ~0ull;
        if (tid == 0) {
            int jj = (int)(unsigned int)(kmin & 0xffffffffu);
            idx[t * NHH + s] = jj;
            c1n[t * NHH + s] = __fsub_rn(c1[jj], c1t);
            c2n[t * NHH + s] = __fsub_rn(c2[jj], c2t);
        }
        __syncthreads();
    }
}

// ---------------- Kernel 2: relative-position bias MLP ----------------
__global__ __launch_bounds__(256) void k_bias(const float* __restrict__ c1n,
                                              const float* __restrict__ c2n,
                                              const float* __restrict__ Wp1,
                                              const float* __restrict__ bp1,
                                              const float* __restrict__ Wp2,
                                              const float* __restrict__ bp2,
                                              float* __restrict__ bias) {
    __shared__ float sWp1[2 * PEHH], sbp1[PEHH], sWp2[PEHH * HEADSS], sbp2[HEADSS];
    int tid = threadIdx.x;
    if (tid < 2 * PEHH) sWp1[tid] = Wp1[tid];
    if (tid < PEHH) sbp1[tid] = bp1[tid];
    if (tid < PEHH * HEADSS) sWp2[tid] = Wp2[tid];
    if (tid < HEADSS) sbp2[tid] = bp2[tid];
    __syncthreads();
    int g = blockIdx.x * 256 + tid;            // T*NH*NH = 1,048,576
    if (g >= TT * NHH * NHH) return;
    int j = g & 15, i = (g >> 4) & 15, t = g >> 8;
    float p1 = c1n[t * NHH + i] - c1n[t * NHH + j];
    float p2 = c2n[t * NHH + i] - c2n[t * NHH + j];
    float acc0 = sbp2[0], acc1 = sbp2[1], acc2 = sbp2[2], acc3 = sbp2[3];
    #pragma unroll
    for (int kk = 0; kk < PEHH; ++kk) {
        float h = lrelu(p1 * sWp1[kk] + p2 * sWp1[PEHH + kk] + sbp1[kk]);
        acc0 += h * sWp2[kk * HEADSS + 0];
        acc1 += h * sWp2[kk * HEADSS + 1];
        acc2 += h * sWp2[kk * HEADSS + 2];
        acc3 += h * sWp2[kk * HEADSS + 3];
    }
    float* bt = bias + (size_t)t * HEADSS * NHH * NHH;
    bt[(0 * NHH + i) * NHH + j] = acc0;
    bt[(1 * NHH + i) * NHH + j] = acc1;
    bt[(2 * NHH + i) * NHH + j] = acc2;
    bt[(3 * NHH + i) * NHH + j] = acc3;
}

// ---------------- Kernel 3: LayerNorm 1 (per (b,t) over 64) ----------------
__global__ __launch_bounds__(256) void k_ln1(const float* __restrict__ x,
                                             const float* __restrict__ g1,
                                             const float* __restrict__ be1,
                                             float* __restrict__ xn) {
    int row = blockIdx.x * 4 + (threadIdx.x >> 6);
    int lane = threadIdx.x & 63;
    float v = x[(size_t)row * MDD + lane];
    float s = v;
    for (int off = 32; off > 0; off >>= 1) s += __shfl_down(s, off);
    s = __shfl(s, 0);
    float m = s * (1.0f / 64.0f);
    float d = v - m;
    float sq = d * d;
    for (int off = 32; off > 0; off >>= 1) sq += __shfl_down(sq, off);
    sq = __shfl(sq, 0);
    float var = sq * (1.0f / 64.0f);
    float inv = 1.0f / sqrtf(var + 1e-5f);
    xn[(size_t)row * MDD + lane] = d * inv * g1[lane] + be1[lane];
}

// ---------------- Kernel 4: per-(b,t) attention + FF block, outputs bf16 xu row ----------------
__global__ __launch_bounds__(256) void k_main(const float* __restrict__ xn,
                                              const int* __restrict__ idx,
                                              const float* __restrict__ bias,
                                              const float* __restrict__ Wq, const float* __restrict__ bq,
                                              const float* __restrict__ Wk, const float* __restrict__ bk,
                                              const float* __restrict__ Wv, const float* __restrict__ bv,
                                              const float* __restrict__ ls,
                                              const float* __restrict__ Wo, const float* __restrict__ bo,
                                              const float* __restrict__ g2, const float* __restrict__ be2,
                                              const float* __restrict__ Wn1, const float* __restrict__ bn1,
                                              const float* __restrict__ Wn2, const float* __restrict__ bn2,
                                              const float* __restrict__ g3, const float* __restrict__ be3,
                                              unsigned short* __restrict__ xu) {
    int n = blockIdx.x;            // b*T + t
    int b = n >> 12;
    int t = n & (TT - 1);
    int tid = threadIdx.x;

    __shared__ float xg[NHH][MDD];
    __shared__ float qs[NHH][MDD];
    __shared__ float ksm[NHH][MDD];
    __shared__ float vs[NHH][MDD];
    __shared__ float att[HEADSS][NHH][NHH];
    __shared__ float hbuf[NHH][FFF];
    __shared__ float red[256], red2[256];
    __shared__ int sidx[NHH];
    __shared__ float rowm[NHH], rowinv[NHH], rows[NHH];

    if (tid < NHH) sidx[tid] = idx[t * NHH + tid];
    __syncthreads();
    for (int o = tid; o < NHH * MDD; o += 256) {
        int r = o >> 6, c = o & 63;
        xg[r][c] = xn[((size_t)b * TT + sidx[r]) * MDD + c];
    }
    __syncthreads();
    {
        int c = tid & 63, r0 = tid >> 6;
        float aq[4], ak[4], av[4];
        #pragma unroll
        for (int u = 0; u < 4; ++u) { aq[u] = bq[c]; ak[u] = bk[c]; av[u] = bv[c]; }
        for (int kk = 0; kk < MDD; ++kk) {
            float wq = Wq[kk * MDD + c], wk = Wk[kk * MDD + c], wv = Wv[kk * MDD + c];
            #pragma unroll
            for (int u = 0; u < 4; ++u) {
                float xv = xg[r0 + 4 * u][kk];
                aq[u] += xv * wq; ak[u] += xv * wk; av[u] += xv * wv;
            }
        }
        #pragma unroll
        for (int u = 0; u < 4; ++u) {
            qs[r0 + 4 * u][c] = aq[u]; ksm[r0 + 4 * u][c] = ak[u]; vs[r0 + 4 * u][c] = av[u];
        }
    }
    __syncthreads();
    if (tid < NHH * HEADSS) {
        int r = tid >> 2, h = tid & 3;
        float sq = 0.0f, sk = 0.0f;
        #pragma unroll
        for (int d = 0; d < DHH; ++d) {
            float qv = qs[r][h * DHH + d]; sq += qv * qv;
            float kv = ksm[r][h * DHH + d]; sk += kv * kv;
        }
        float iq = 1.0f / fmaxf(sqrtf(sq), 1e-6f);
        float ik = 1.0f / fmaxf(sqrtf(sk), 1e-6f);
        #pragma unroll
        for (int d = 0; d < DHH; ++d) {
            qs[r][h * DHH + d] *= iq;
            ksm[r][h * DHH + d] *= ik;
        }
    }
    __syncthreads();
    for (int o = tid; o < HEADSS * NHH * NHH; o += 256) {
        int j = o & 15, i = (o >> 4) & 15, h = o >> 8;
        float s = 0.0f;
        #pragma unroll
        for (int d = 0; d < DHH; ++d) s += qs[i][h * DHH + d] * ksm[j][h * DHH + d];
        float scale = expf(fminf(ls[h], 4.60517018598809136804f));
        s = s * scale + bias[(((size_t)t * HEADSS + h) * NHH + i) * NHH + j];
        att[h][i][j] = s;
    }
    __syncthreads();
    if (tid < HEADSS * NHH) {
        int h = tid >> 4, i = tid & 15;
        float mx = att[h][i][0];
        #pragma unroll
        for (int j = 1; j < NHH; ++j) mx = fmaxf(mx, att[h][i][j]);
        float sm = 0.0f;
        #pragma unroll
        for (int j = 0; j < NHH; ++j) { float e = expf(att[h][i][j] - mx); att[h][i][j] = e; sm += e; }
        float inv = 1.0f / sm;
        #pragma unroll
        for (int j = 0; j < NHH; ++j) att[h][i][j] *= inv;
    }
    __syncthreads();
    for (int o = tid; o < NHH * MDD; o += 256) {
        int r = o >> 6, c = o & 63;
        int h = c >> 4;
        float s = 0.0f;
        #pragma unroll
        for (int j = 0; j < NHH; ++j) s += att[h][r][j] * vs[j][c];
        qs[r][c] = s;
    }
    __syncthreads();
    {
        int c = tid & 63, r0 = tid >> 6;
        float a[4];
        #pragma unroll
        for (int u = 0; u < 4; ++u) a[u] = bo[c];
        for (int kk = 0; kk < MDD; ++kk) {
            float w = Wo[kk * MDD + c];
            #pragma unroll
            for (int u = 0; u < 4; ++u) a[u] += qs[r0 + 4 * u][kk] * w;
        }
        __syncthreads();
        #pragma unroll
        for (int u = 0; u < 4; ++u) ksm[r0 + 4 * u][c] = xg[r0 + 4 * u][c] + a[u];
    }
    __syncthreads();
    {
        int r = tid >> 4, s4 = tid & 15;
        float ps = 0.0f, pq = 0.0f;
        #pragma unroll
        for (int u = 0; u < 4; ++u) { float v = ksm[r][s4 * 4 + u]; ps += v; pq += v * v; }
        red[tid] = ps; red2[tid] = pq;
    }
    __syncthreads();
    if (tid < NHH) {
        float s = 0.0f, q = 0.0f;
        #pragma unroll
        for (int u = 0; u < 16; ++u) { s += red[tid * 16 + u]; q += red2[tid * 16 + u]; }
        float m = s * (1.0f / 64.0f);
        float var = q * (1.0f / 64.0f) - m * m;
        rowm[tid] = m;
        rowinv[tid] = 1.0f / sqrtf(var + 1e-5f);
    }
    __syncthreads();
    for (int o = tid; o < NHH * MDD; o += 256) {
        int r = o >> 6, c = o & 63;
        vs[r][c] = (ksm[r][c] - rowm[r]) * rowinv[r] * g2[c] + be2[c];
    }
    __syncthreads();
    {
        int j = tid;
        float a[NHH];
        #pragma unroll
        for (int r = 0; r < NHH; ++r) a[r] = bn1[j];
        for (int kk = 0; kk < MDD; ++kk) {
            float w = Wn1[kk * FFF + j];
            #pragma unroll
            for (int r = 0; r < NHH; ++r) a[r] += vs[r][kk] * w;
        }
        #pragma unroll
        for (int r = 0; r < NHH; ++r) hbuf[r][j] = lrelu(a[r]);
    }
    __syncthreads();
    {
        int r = tid >> 4, s4 = tid & 15;
        float a = 0.0f;
        #pragma unroll
        for (int u = 0; u < 16; ++u) a += hbuf[r][s4 * 16 + u] * Wn2[s4 * 16 + u];
        red[tid] = a;
    }
    __syncthreads();
    if (tid < NHH) {
        float a = bn2[0];
        #pragma unroll
        for (int u = 0; u < 16; ++u) a += red[tid * 16 + u];
        rows[tid] = lrelu(a);
    }
    __syncthreads();
    {
        float ps = 0.0f, pq = 0.0f;
        #pragma unroll
        for (int u = 0; u < 4; ++u) {
            int o = tid * 4 + u;
            int r = o >> 6, c = o & 63;
            float v = vs[r][c] + rows[r];
            vs[r][c] = v;
            ps += v; pq += v * v;
        }
        red[tid] = ps; red2[tid] = pq;
    }
    __syncthreads();
    for (int off = 128; off > 0; off >>= 1) {
        if (tid < off) { red[tid] += red[tid + off]; red2[tid] += red2[tid + off]; }
        __syncthreads();
    }
    float m = red[0] * (1.0f / 1024.0f);
    float var = red2[0] * (1.0f / 1024.0f) - m * m;
    float inv = 1.0f / sqrtf(var + 1e-5f);
    #pragma unroll
    for (int u = 0; u < 4; ++u) {
        int o = tid * 4 + u;
        int r = o >> 6, c = o & 63;
        xu[(size_t)n * 1024 + o] = f2bf((vs[r][c] - m) * inv * g3[o] + be3[o]);
    }
}

// ---------------- Kernel 5a: transpose + convert Wu1 -> bf16 Wu1t[n][k] ----------------
__global__ __launch_bounds__(256) void k_cvtW(const float* __restrict__ W,
                                              unsigned short* __restrict__ Wt) {
    __shared__ float tile[32][33];
    int tk = blockIdx.x & 31;
    int tn = blockIdx.x >> 5;
    int c = threadIdx.x & 31, r4 = threadIdx.x >> 5;
    #pragma unroll
    for (int p = 0; p < 4; ++p) {
        int r = p * 8 + r4;
        tile[r][c] = W[(size_t)(tk * 32 + r) * GN + tn * 32 + c];
    }
    __syncthreads();
    #pragma unroll
    for (int p = 0; p < 4; ++p) {
        int r = p * 8 + r4;   // n-local
        Wt[(size_t)(tn * 32 + r) * GK + tk * 32 + c] = f2bf(tile[c][r]);
    }
}

// ---------------- Kernel 5b: MFMA GEMM xu@Wu1 fused with bu1+lrelu+Wu2 row-dot ----------------
__global__ __launch_bounds__(256) void k_gemm(const unsigned short* __restrict__ xu,
                                              const unsigned short* __restrict__ Wt,
                                              const float* __restrict__ bu1,
                                              const float* __restrict__ Wu2,
                                              float* __restrict__ partial) {
    int bm = blockIdx.x;          // 0..255
    int bn = blockIdx.y;          // 0..7
    int tid = threadIdx.x;
    int w = tid >> 6, l = tid & 63;
    int wm = w >> 1, wn = w & 1;
    int lr = l & 15, lg = l >> 4;

    __shared__ unsigned short As[BMt * BKt];   // 16 KB, [128 rows][64 k], XOR-swizzled 16B slots
    __shared__ unsigned short Bs[BNt * BKt];   // 16 KB, [128 n][64 k], same swizzle
    __shared__ float rowpart[2][BMt];

    f32x4 acc[4][4];
    #pragma unroll
    for (int i = 0; i < 4; ++i)
        #pragma unroll
        for (int j = 0; j < 4; ++j)
            acc[i][j] = (f32x4){0.0f, 0.0f, 0.0f, 0.0f};

    char* Ab = reinterpret_cast<char*>(As);
    char* Bb = reinterpret_cast<char*>(Bs);

    for (int k0 = 0; k0 < GK; k0 += BKt) {
        __syncthreads();
        // stage A (128x64) and B (128x64), 16B per thread per pass, swizzled dest
        #pragma unroll
        for (int p = 0; p < 4; ++p) {
            int s = p * 256 + tid;          // 0..1023
            int r = s >> 3, c8 = s & 7;     // row, 16B-slot
            int off = r * 128 + ((c8 * 16) ^ ((r & 7) << 4));
            uint4 va = *reinterpret_cast<const uint4*>(xu + ((size_t)(bm * BMt + r)) * GK + k0 + c8 * 8);
            *reinterpret_cast<uint4*>(Ab + off) = va;
            uint4 vb = *reinterpret_cast<const uint4*>(Wt + ((size_t)(bn * BNt + r)) * GK + k0 + c8 * 8);
            *reinterpret_cast<uint4*>(Bb + off) = vb;
        }
        __syncthreads();
        #pragma unroll
        for (int ks = 0; ks < 2; ++ks) {
            bf16x8 af[4], bfr[4];
            #pragma unroll
            for (int rf = 0; rf < 4; ++rf) {
                int row = wm * 64 + rf * 16 + lr;
                int coff = (ks * 64 + lg * 16) ^ ((row & 7) << 4);
                af[rf] = *reinterpret_cast<const bf16x8*>(Ab + row * 128 + coff);
            }
            #pragma unroll
            for (int nf = 0; nf < 4; ++nf) {
                int rowb = wn * 64 + nf * 16 + lr;
                int coff = (ks * 64 + lg * 16) ^ ((rowb & 7) << 4);
                bfr[nf] = *reinterpret_cast<const bf16x8*>(Bb + rowb * 128 + coff);
            }
            #pragma unroll
            for (int rf = 0; rf < 4; ++rf)
                #pragma unroll
                for (int nf = 0; nf < 4; ++nf)
                    acc[rf][nf] = __builtin_amdgcn_mfma_f32_16x16x32_bf16(af[rf], bfr[nf], acc[rf][nf], 0, 0, 0);
        }
    }

    // epilogue: p = lrelu(acc + bu1[n]) * Wu2[n]; reduce over n
    float b1v[4], w2v[4];
    #pragma unroll
    for (int nf = 0; nf < 4; ++nf) {
        int nn = bn * BNt + wn * 64 + nf * 16 + lr;
        b1v[nf] = bu1[nn];
        w2v[nf] = Wu2[nn];
    }
    float rowsum[4][4];   // [rf][j]
    #pragma unroll
    for (int rf = 0; rf < 4; ++rf) {
        #pragma unroll
        for (int j = 0; j < 4; ++j) {
            float s = 0.0f;
            #pragma unroll
            for (int nf = 0; nf < 4; ++nf)
                s += lrelu(acc[rf][nf][j] + b1v[nf]) * w2v[nf];
            // reduce across the 16 lanes of this row group (lanes differing in low 4 bits)
            #pragma unroll
            for (int off = 1; off < 16; off <<= 1)
                s += __shfl_xor(s, off);
            rowsum[rf][j] = s;
        }
    }
    if (lr == 0) {
        #pragma unroll
        for (int rf = 0; rf < 4; ++rf)
            #pragma unroll
            for (int j = 0; j < 4; ++j)
                rowpart[wn][wm * 64 + rf * 16 + lg * 4 + j] = rowsum[rf][j];
    }
    __syncthreads();
    if (tid < BMt) {
        float v = rowpart[0][tid] + rowpart[1][tid];
        partial[((size_t)(bm * BMt + tid)) * NCHUNK + bn] = v;
    }
}

// ---------------- Kernel 5c: sum partials + bias + lrelu ----------------
__global__ __launch_bounds__(256) void k_reduce(const float* __restrict__ partial,
                                                const float* __restrict__ bu2,
                                                float* __restrict__ out) {
    int m = blockIdx.x * 256 + threadIdx.x;
    float s = bu2[0];
    #pragma unroll
    for (int c = 0; c < NCHUNK; ++c) s += partial[(size_t)m * NCHUNK + c];
    out[m] = lrelu(s);
}

extern "C" void kernel_launch(void* const* d_in, const int* in_sizes, int n_in,
                              void* d_out, int out_size, void* d_ws, size_t ws_size,
                              hipStream_t stream) {
    const float* x   = (const float*)d_in[0];
    const float* c1  = (const float*)d_in[1];
    const float* c2  = (const float*)d_in[2];
    const float* g1  = (const float*)d_in[3];
    const float* be1 = (const float*)d_in[4];
    const float* Wq  = (const float*)d_in[5];
    const float* bq  = (const float*)d_in[6];
    const float* Wk  = (const float*)d_in[7];
    const float* bk  = (const float*)d_in[8];
    const float* Wv  = (const float*)d_in[9];
    const float* bv  = (const float*)d_in[10];
    const float* ls  = (const float*)d_in[11];
    const float* Wo  = (const float*)d_in[12];
    const float* bo  = (const float*)d_in[13];
    const float* Wp1 = (const float*)d_in[14];
    const float* bp1 = (const float*)d_in[15];
    const float* Wp2 = (const float*)d_in[16];
    const float* bp2 = (const float*)d_in[17];
    const float* g2  = (const float*)d_in[18];
    const float* be2 = (const float*)d_in[19];
    const float* Wn1 = (const float*)d_in[20];
    const float* bn1 = (const float*)d_in[21];
    const float* Wn2 = (const float*)d_in[22];
    const float* bn2 = (const float*)d_in[23];
    const float* g3  = (const float*)d_in[24];
    const float* be3 = (const float*)d_in[25];
    const float* Wu1 = (const float*)d_in[26];
    const float* bu1 = (const float*)d_in[27];
    const float* Wu2 = (const float*)d_in[28];
    const float* bu2 = (const float*)d_in[29];
    float* out = (float*)d_out;

    char* ws = (char*)d_ws;
    size_t off = 0;
    int*   idx  = (int*)(ws + off);   off += (size_t)TT * NHH * 4;                 // 256 KB
    float* c1n  = (float*)(ws + off); off += (size_t)TT * NHH * 4;                 // 256 KB
    float* c2n  = (float*)(ws + off); off += (size_t)TT * NHH * 4;                 // 256 KB
    float* bias = (float*)(ws + off); off += (size_t)TT * HEADSS * NHH * NHH * 4;  // 16 MB
    float* xn   = (float*)(ws + off); off += (size_t)BB * TT * MDD * 4;            // 8 MB
    unsigned short* xuB  = (unsigned short*)(ws + off); off += (size_t)GM * GK * 2;   // 64 MB
    unsigned short* Wu1t = (unsigned short*)(ws + off); off += (size_t)GK * GN * 2;   // 2 MB
    float* partial = (float*)(ws + off); off += (size_t)GM * NCHUNK * 4;           // 1 MB

    k_neighbors<<<TT, 256, 0, stream>>>(c1, c2, idx, c1n, c2n);
    k_bias<<<(TT * NHH * NHH + 255) / 256, 256, 0, stream>>>(c1n, c2n, Wp1, bp1, Wp2, bp2, bias);
    k_ln1<<<(BB * TT) / 4, 256, 0, stream>>>(x, g1, be1, xn);
    k_cvtW<<<1024, 256, 0, stream>>>(Wu1, Wu1t);
    k_main<<<BB * TT, 256, 0, stream>>>(xn, idx, bias, Wq, bq, Wk, bk, Wv, bv, ls, Wo, bo,
                                        g2, be2, Wn1, bn1, Wn2, bn2, g3, be3, xuB);
    k_gemm<<<dim3(GM / BMt, GN / BNt), 256, 0, stream>>>(xuB, Wu1t, bu1, Wu2, partial);
    k_reduce<<<GM / 256, 256, 0, stream>>>(partial, bu2, out);
}

// Round 3
// 579.793 us; speedup vs baseline: 8.2959x; 2.1427x over previous
//
#include <hip/hip_runtime.h>
#include <hip/hip_bf16.h>

#define BB 8
#define TT 4096
#define NHH 16
#define MDD 64
#define FFF 256
#define HEADSS 4
#define DHH 16
#define PEHH 32

#define GM (BB * TT)      // 32768
#define GK 1024
#define GN 1024
#define BMt 128
#define BNt 128
#define BKt 64
#define NCHUNK (GN / BNt) // 8

typedef float f32x4 __attribute__((ext_vector_type(4)));
typedef short bf16x8 __attribute__((ext_vector_type(8)));

static __device__ __forceinline__ float lrelu(float x) { return x > 0.0f ? x : 0.2f * x; }
static __device__ __forceinline__ unsigned long long umin64(unsigned long long a, unsigned long long b) {
    return a < b ? a : b;
}
static __device__ __forceinline__ unsigned short f2bf(float f) {
    unsigned u = __float_as_uint(f);
    u = u + 0x7fffu + ((u >> 16) & 1u);   // RNE
    return (unsigned short)(u >> 16);
}
static __device__ __forceinline__ float bf2f(unsigned short u) {
    return __uint_as_float(((unsigned)u) << 16);
}

// ---------------- Kernel 1: 16-NN search per token (batch-independent) ----------------
__global__ __launch_bounds__(256) void k_neighbors(const float* __restrict__ c1,
                                                   const float* __restrict__ c2,
                                                   int* __restrict__ idx,
                                                   float* __restrict__ c1n,
                                                   float* __restrict__ c2n) {
    int t = blockIdx.x;
    int tid = threadIdx.x;
    __shared__ unsigned long long keys[TT];   // 32 KB
    __shared__ unsigned long long red[256];
    float c1t = c1[t], c2t = c2[t];
    for (int j = tid; j < TT; j += 256) {
        float d1 = __fsub_rn(c1[j], c1t);
        float d2 = __fsub_rn(c2[j], c2t);
        float dist = __fadd_rn(__fmul_rn(d1, d1), __fmul_rn(d2, d2));
        unsigned long long db = (unsigned long long)__float_as_uint(dist);
        keys[j] = (db << 32) | (unsigned int)j;   // ties -> lower index (top_k stable)
    }
    __syncthreads();
    for (int s = 0; s < NHH; ++s) {
        unsigned long long m = ~0ull;
        for (int j = tid; j < TT; j += 256) m = umin64(m, keys[j]);
        red[tid] = m;
        __syncthreads();
        for (int off = 128; off > 0; off >>= 1) {
            if (tid < off) red[tid] = umin64(red[tid], red[tid + off]);
            __syncthreads();
        }
        unsigned long long kmin = red[0];
        for (int j = tid; j < TT; j += 256)
            if (keys[j] == kmin) keys[j] = ~0ull;
        if (tid == 0) {
            int jj = (int)(unsigned int)(kmin & 0xffffffffu);
            idx[t * NHH + s] = jj;
            c1n[t * NHH + s] = __fsub_rn(c1[jj], c1t);
            c2n[t * NHH + s] = __fsub_rn(c2[jj], c2t);
        }
        __syncthreads();
    }
}

// ---------------- Kernel 2: relative-position bias MLP ----------------
__global__ __launch_bounds__(256) void k_bias(const float* __restrict__ c1n,
                                              const float* __restrict__ c2n,
                                              const float* __restrict__ Wp1,
                                              const float* __restrict__ bp1,
                                              const float* __restrict__ Wp2,
                                              const float* __restrict__ bp2,
                                              float* __restrict__ bias) {
    __shared__ float sWp1[2 * PEHH], sbp1[PEHH], sWp2[PEHH * HEADSS], sbp2[HEADSS];
    int tid = threadIdx.x;
    if (tid < 2 * PEHH) sWp1[tid] = Wp1[tid];
    if (tid < PEHH) sbp1[tid] = bp1[tid];
    if (tid < PEHH * HEADSS) sWp2[tid] = Wp2[tid];
    if (tid < HEADSS) sbp2[tid] = bp2[tid];
    __syncthreads();
    int g = blockIdx.x * 256 + tid;            // T*NH*NH = 1,048,576
    if (g >= TT * NHH * NHH) return;
    int j = g & 15, i = (g >> 4) & 15, t = g >> 8;
    float p1 = c1n[t * NHH + i] - c1n[t * NHH + j];
    float p2 = c2n[t * NHH + i] - c2n[t * NHH + j];
    float acc0 = sbp2[0], acc1 = sbp2[1], acc2 = sbp2[2], acc3 = sbp2[3];
    #pragma unroll
    for (int kk = 0; kk < PEHH; ++kk) {
        float h = lrelu(p1 * sWp1[kk] + p2 * sWp1[PEHH + kk] + sbp1[kk]);
        acc0 += h * sWp2[kk * HEADSS + 0];
        acc1 += h * sWp2[kk * HEADSS + 1];
        acc2 += h * sWp2[kk * HEADSS + 2];
        acc3 += h * sWp2[kk * HEADSS + 3];
    }
    float* bt = bias + (size_t)t * HEADSS * NHH * NHH;
    bt[(0 * NHH + i) * NHH + j] = acc0;
    bt[(1 * NHH + i) * NHH + j] = acc1;
    bt[(2 * NHH + i) * NHH + j] = acc2;
    bt[(3 * NHH + i) * NHH + j] = acc3;
}

// ---------------- Kernel 3: LayerNorm 1, writes bf16 ----------------
__global__ __launch_bounds__(256) void k_ln1(const float* __restrict__ x,
                                             const float* __restrict__ g1,
                                             const float* __restrict__ be1,
                                             unsigned short* __restrict__ xn) {
    int row = blockIdx.x * 4 + (threadIdx.x >> 6);
    int lane = threadIdx.x & 63;
    float v = x[(size_t)row * MDD + lane];
    float s = v;
    for (int off = 32; off > 0; off >>= 1) s += __shfl_down(s, off);
    s = __shfl(s, 0);
    float m = s * (1.0f / 64.0f);
    float d = v - m;
    float sq = d * d;
    for (int off = 32; off > 0; off >>= 1) sq += __shfl_down(sq, off);
    sq = __shfl(sq, 0);
    float var = sq * (1.0f / 64.0f);
    float inv = 1.0f / sqrtf(var + 1e-5f);
    xn[(size_t)row * MDD + lane] = f2bf(d * inv * g1[lane] + be1[lane]);
}

// ---------------- Kernel 3b: pre-transpose small weights to bf16 [n][k] ----------------
__global__ __launch_bounds__(256) void k_prepw(const float* __restrict__ Wq, const float* __restrict__ Wk,
                                               const float* __restrict__ Wv, const float* __restrict__ Wo,
                                               const float* __restrict__ Wn1,
                                               unsigned short* __restrict__ Wqkvt,
                                               unsigned short* __restrict__ Wot,
                                               unsigned short* __restrict__ Wn1t) {
    int id = blockIdx.x * 256 + threadIdx.x;   // 128 blocks -> 32768 elems
    if (id < 12288) {
        int n = id >> 6, kk = id & 63;
        float v = (n < 64) ? Wq[kk * 64 + n] : (n < 128) ? Wk[kk * 64 + (n - 64)] : Wv[kk * 64 + (n - 128)];
        Wqkvt[id] = f2bf(v);
    } else if (id < 16384) {
        int j = id - 12288;
        int n = j >> 6, kk = j & 63;
        Wot[j] = f2bf(Wo[kk * 64 + n]);
    } else {
        int j = id - 16384;
        int n = j >> 6, kk = j & 63;
        Wn1t[j] = f2bf(Wn1[kk * 256 + n]);
    }
}

// ---------------- Kernel 4: fused MFMA block kernel, 4 tokens/block ----------------
__global__ __launch_bounds__(256) void k_main(const unsigned short* __restrict__ xnb,
                                              const int* __restrict__ idx,
                                              const float* __restrict__ bias,
                                              const unsigned short* __restrict__ Wqkvt,
                                              const unsigned short* __restrict__ Wot,
                                              const unsigned short* __restrict__ Wn1t,
                                              const float* __restrict__ bq, const float* __restrict__ bk,
                                              const float* __restrict__ bv, const float* __restrict__ ls,
                                              const float* __restrict__ bo,
                                              const float* __restrict__ g2, const float* __restrict__ be2,
                                              const float* __restrict__ bn1, const float* __restrict__ Wn2,
                                              const float* __restrict__ bn2,
                                              const float* __restrict__ g3, const float* __restrict__ be3,
                                              unsigned short* __restrict__ xu) {
    __shared__ __align__(16) char L[65536];
    char* R0 = L;            // xg 8K  -> xu staging
    char* R1 = L + 8192;     // Wqkv 24K -> Wn1 rows 0..191
    char* R2 = L + 32768;    // q 8K -> av
    char* R3 = L + 40960;    // k 8K -> Wn1 rows 192..255
    char* R4 = L + 49152;    // v 8K -> xfn
    char* R5 = L + 57344;    // Wo 8K

    const int tid = threadIdx.x;
    const int lane = tid & 63;
    const int li = lane & 15;
    const int G = lane >> 4;
    const int tok = tid >> 6;
    const int nglob = blockIdx.x * 4 + tok;
    const int t = nglob & (TT - 1);

    // ---- stage 1: gather xg (bf16) + Wqkv ----
    {
        int row = tid >> 2, part = tid & 3;
        int rn = blockIdx.x * 4 + (row >> 4);
        int rb = rn >> 12, rt = rn & (TT - 1);
        int j = idx[rt * NHH + (row & 15)];
        const uint4* sp = reinterpret_cast<const uint4*>(xnb + ((size_t)rb * TT + j) * MDD + part * 16);
        uint4 w0 = sp[0], w1 = sp[1];
        int sw = (row & 7) << 4;
        *reinterpret_cast<uint4*>(R0 + row * 128 + ((part * 32) ^ sw)) = w0;
        *reinterpret_cast<uint4*>(R0 + row * 128 + ((part * 32 + 16) ^ sw)) = w1;
    }
    for (int s = tid; s < 1536; s += 256) {
        int rw = s >> 3, sl = s & 7;
        uint4 w = *reinterpret_cast<const uint4*>(Wqkvt + rw * 64 + sl * 8);
        *reinterpret_cast<uint4*>(R1 + rw * 128 + ((sl * 16) ^ ((rw & 7) << 4))) = w;
    }
    __syncthreads();

    // ---- QKV GEMM (M=64, N=192, K=64); wave = token (M-tile) ----
    {
        f32x4 acc[12];
        #pragma unroll
        for (int i = 0; i < 12; ++i) acc[i] = (f32x4){0.0f, 0.0f, 0.0f, 0.0f};
        const int arow = tok * 16 + li;
        const int asw = (arow & 7) << 4;
        #pragma unroll
        for (int ks = 0; ks < 2; ++ks) {
            bf16x8 af = *reinterpret_cast<const bf16x8*>(R0 + arow * 128 + ((ks * 64 + G * 16) ^ asw));
            #pragma unroll
            for (int nt = 0; nt < 12; ++nt) {
                int n = nt * 16 + li;
                bf16x8 bfv = *reinterpret_cast<const bf16x8*>(R1 + n * 128 + ((ks * 64 + G * 16) ^ ((n & 7) << 4)));
                acc[nt] = __builtin_amdgcn_mfma_f32_16x16x32_bf16(af, bfv, acc[nt], 0, 0, 0);
            }
        }
        // epilogue: +bias, L2-normalize q,k per (row, head); write bf16 to q/k/v LDS
        #pragma unroll
        for (int h = 0; h < 4; ++h) {
            int c = h * 16 + li;
            float bqv = bq[c], bkv = bk[c], bvv = bv[c];
            float qv[4], kv[4], vv[4];
            #pragma unroll
            for (int r = 0; r < 4; ++r) {
                qv[r] = acc[h][r] + bqv;
                kv[r] = acc[4 + h][r] + bkv;
                vv[r] = acc[8 + h][r] + bvv;
            }
            #pragma unroll
            for (int r = 0; r < 4; ++r) {
                float sq = qv[r] * qv[r];
                sq += __shfl_xor(sq, 1); sq += __shfl_xor(sq, 2); sq += __shfl_xor(sq, 4); sq += __shfl_xor(sq, 8);
                float sk = kv[r] * kv[r];
                sk += __shfl_xor(sk, 1); sk += __shfl_xor(sk, 2); sk += __shfl_xor(sk, 4); sk += __shfl_xor(sk, 8);
                float iq = 1.0f / fmaxf(sqrtf(sq), 1e-6f);
                float ik = 1.0f / fmaxf(sqrtf(sk), 1e-6f);
                int row = tok * 16 + G * 4 + r;
                int sw = (row & 7) << 4;
                *reinterpret_cast<unsigned short*>(R2 + row * 128 + ((c * 2) ^ sw)) = f2bf(qv[r] * iq);
                *reinterpret_cast<unsigned short*>(R3 + row * 128 + ((c * 2) ^ sw)) = f2bf(kv[r] * ik);
                *reinterpret_cast<unsigned short*>(R4 + row * 128 + ((c * 2) ^ sw)) = f2bf(vv[r]);
            }
        }
    }
    __syncthreads();
    // ---- stage 2: Wo -> R5, Wn1 rows 0..191 -> R1 ----
    for (int s = tid; s < 2048; s += 256) {
        if (s < 512) {
            int rw = s >> 3, sl = s & 7;
            uint4 w = *reinterpret_cast<const uint4*>(Wot + rw * 64 + sl * 8);
            *reinterpret_cast<uint4*>(R5 + rw * 128 + ((sl * 16) ^ ((rw & 7) << 4))) = w;
        } else {
            int s2 = s - 512;
            int rw = s2 >> 3, sl = s2 & 7;
            uint4 w = *reinterpret_cast<const uint4*>(Wn1t + rw * 64 + sl * 8);
            *reinterpret_cast<uint4*>(R1 + rw * 128 + ((sl * 16) ^ ((rw & 7) << 4))) = w;
        }
    }
    __syncthreads();

    // ---- attention (wave-local, per head): S^T = mfma(K, Q), softmax, PV ----
    {
        const int jrow = tok * 16 + li;
        const int jsw = (jrow & 7) << 4;
        #pragma unroll
        for (int h = 0; h < 4; ++h) {
            f32x4 s4 = (f32x4){0.0f, 0.0f, 0.0f, 0.0f};
            bf16x8 af = {}, bfv = {};
            if (G < 2) {
                af  = *reinterpret_cast<const bf16x8*>(R3 + jrow * 128 + ((h * 32 + G * 16) ^ jsw));
                bfv = *reinterpret_cast<const bf16x8*>(R2 + jrow * 128 + ((h * 32 + G * 16) ^ jsw));
            }
            s4 = __builtin_amdgcn_mfma_f32_16x16x32_bf16(af, bfv, s4, 0, 0, 0);
            // lane holds S^T[j = G*4+r][i = li]
            float sc = __expf(fminf(ls[h], 4.60517018598809136804f));
            const float4 b4 = *reinterpret_cast<const float4*>(bias + ((size_t)t * 4 + h) * 256 + li * 16 + G * 4);
            float attv[4];
            attv[0] = s4[0] * sc + b4.x;
            attv[1] = s4[1] * sc + b4.y;
            attv[2] = s4[2] * sc + b4.z;
            attv[3] = s4[3] * sc + b4.w;
            float mx = fmaxf(fmaxf(attv[0], attv[1]), fmaxf(attv[2], attv[3]));
            mx = fmaxf(mx, __shfl_xor(mx, 16));
            mx = fmaxf(mx, __shfl_xor(mx, 32));
            float e[4];
            float sm = 0.0f;
            #pragma unroll
            for (int r = 0; r < 4; ++r) { e[r] = __expf(attv[r] - mx); sm += e[r]; }
            sm += __shfl_xor(sm, 16);
            sm += __shfl_xor(sm, 32);
            float inv = 1.0f / sm;
            // pack unnormalized e as bf16; build PV A-frag (P rows) via shfl
            unsigned p01 = (unsigned)f2bf(e[0]) | ((unsigned)f2bf(e[1]) << 16);
            unsigned p23 = (unsigned)f2bf(e[2]) | ((unsigned)f2bf(e[3]) << 16);
            int s0l = li + 32 * (G & 1);
            unsigned w0 = (unsigned)__shfl((int)p01, s0l);
            unsigned w1 = (unsigned)__shfl((int)p23, s0l);
            unsigned w2 = (unsigned)__shfl((int)p01, s0l + 16);
            unsigned w3 = (unsigned)__shfl((int)p23, s0l + 16);
            uint4 aw;
            if (G < 2) { aw.x = w0; aw.y = w1; aw.z = w2; aw.w = w3; }
            else       { aw.x = 0;  aw.y = 0;  aw.z = 0;  aw.w = 0;  }
            uint4 bw = {0, 0, 0, 0};
            if (G < 2) {
                unsigned bwv[4] = {0, 0, 0, 0};
                #pragma unroll
                for (int jj = 0; jj < 8; ++jj) {
                    int row = tok * 16 + G * 8 + jj;
                    unsigned short vvv = *reinterpret_cast<const unsigned short*>(
                        R4 + row * 128 + (((h * 16 + li) * 2) ^ ((row & 7) << 4)));
                    bwv[jj >> 1] |= ((unsigned)vvv) << (16 * (jj & 1));
                }
                bw.x = bwv[0]; bw.y = bwv[1]; bw.z = bwv[2]; bw.w = bwv[3];
            }
            f32x4 pv = (f32x4){0.0f, 0.0f, 0.0f, 0.0f};
            pv = __builtin_amdgcn_mfma_f32_16x16x32_bf16(
                     __builtin_bit_cast(bf16x8, aw), __builtin_bit_cast(bf16x8, bw), pv, 0, 0, 0);
            // av[i = G*4+r][h*16+li] -> R2 (q region, head h cols already consumed)
            #pragma unroll
            for (int r = 0; r < 4; ++r) {
                int row = tok * 16 + G * 4 + r;
                *reinterpret_cast<unsigned short*>(R2 + row * 128 + (((h * 16 + li) * 2) ^ ((row & 7) << 4)))
                    = f2bf(pv[r] * inv);
            }
        }
    }
    __syncthreads();
    // ---- stage 3: Wn1 rows 192..255 -> R3 ----
    for (int s = tid; s < 512; s += 256) {
        int rw = s >> 3, sl = s & 7;
        uint4 w = *reinterpret_cast<const uint4*>(Wn1t + (192 + rw) * 64 + sl * 8);
        *reinterpret_cast<uint4*>(R3 + rw * 128 + ((sl * 16) ^ ((rw & 7) << 4))) = w;
    }
    __syncthreads();

    // ---- out-proj + residual + LN2 -> xfn (R4) ----
    float xfnv[4][4];
    float rowadd[4];
    {
        f32x4 oacc[4];
        #pragma unroll
        for (int i = 0; i < 4; ++i) oacc[i] = (f32x4){0.0f, 0.0f, 0.0f, 0.0f};
        const int arow = tok * 16 + li;
        const int asw = (arow & 7) << 4;
        #pragma unroll
        for (int ks = 0; ks < 2; ++ks) {
            bf16x8 af = *reinterpret_cast<const bf16x8*>(R2 + arow * 128 + ((ks * 64 + G * 16) ^ asw));
            #pragma unroll
            for (int nt = 0; nt < 4; ++nt) {
                int n = nt * 16 + li;
                bf16x8 bfv = *reinterpret_cast<const bf16x8*>(R5 + n * 128 + ((ks * 64 + G * 16) ^ ((n & 7) << 4)));
                oacc[nt] = __builtin_amdgcn_mfma_f32_16x16x32_bf16(af, bfv, oacc[nt], 0, 0, 0);
            }
        }
        float xf[4][4];
        float s[4] = {0, 0, 0, 0}, sq[4] = {0, 0, 0, 0};
        #pragma unroll
        for (int nt = 0; nt < 4; ++nt) {
            int c = nt * 16 + li;
            float bov = bo[c];
            #pragma unroll
            for (int r = 0; r < 4; ++r) {
                int row = tok * 16 + G * 4 + r;
                unsigned short xgv = *reinterpret_cast<const unsigned short*>(
                    R0 + row * 128 + ((c * 2) ^ ((row & 7) << 4)));
                float v = oacc[nt][r] + bov + bf2f(xgv);
                xf[nt][r] = v;
                s[r] += v; sq[r] += v * v;
            }
        }
        float m[4], inv[4];
        #pragma unroll
        for (int r = 0; r < 4; ++r) {
            float ss = s[r];
            ss += __shfl_xor(ss, 1); ss += __shfl_xor(ss, 2); ss += __shfl_xor(ss, 4); ss += __shfl_xor(ss, 8);
            float qq = sq[r];
            qq += __shfl_xor(qq, 1); qq += __shfl_xor(qq, 2); qq += __shfl_xor(qq, 4); qq += __shfl_xor(qq, 8);
            m[r] = ss * (1.0f / 64.0f);
            float var = qq * (1.0f / 64.0f) - m[r] * m[r];
            inv[r] = 1.0f / sqrtf(var + 1e-5f);
        }
        #pragma unroll
        for (int nt = 0; nt < 4; ++nt) {
            int c = nt * 16 + li;
            float g2v = g2[c], be2v = be2[c];
            #pragma unroll
            for (int r = 0; r < 4; ++r) {
                int row = tok * 16 + G * 4 + r;
                float v = (xf[nt][r] - m[r]) * inv[r] * g2v + be2v;
                xfnv[nt][r] = v;
                *reinterpret_cast<unsigned short*>(R4 + row * 128 + ((c * 2) ^ ((row & 7) << 4))) = f2bf(v);
            }
        }
    }

    // ---- FF1 (N=256) + FF2 row-dot ----
    {
        f32x4 facc[16];
        #pragma unroll
        for (int i = 0; i < 16; ++i) facc[i] = (f32x4){0.0f, 0.0f, 0.0f, 0.0f};
        const int arow = tok * 16 + li;
        const int asw = (arow & 7) << 4;
        #pragma unroll
        for (int ks = 0; ks < 2; ++ks) {
            bf16x8 af = *reinterpret_cast<const bf16x8*>(R4 + arow * 128 + ((ks * 64 + G * 16) ^ asw));
            #pragma unroll
            for (int nt = 0; nt < 16; ++nt) {
                int n = nt * 16 + li;
                const char* base = (n < 192) ? (R1 + n * 128) : (R3 + (n - 192) * 128);
                bf16x8 bfv = *reinterpret_cast<const bf16x8*>(base + ((ks * 64 + G * 16) ^ ((n & 7) << 4)));
                facc[nt] = __builtin_amdgcn_mfma_f32_16x16x32_bf16(af, bfv, facc[nt], 0, 0, 0);
            }
        }
        float dot[4] = {0, 0, 0, 0};
        #pragma unroll
        for (int nt = 0; nt < 16; ++nt) {
            int n = nt * 16 + li;
            float b1 = bn1[n], w2 = Wn2[n];
            #pragma unroll
            for (int r = 0; r < 4; ++r) dot[r] += lrelu(facc[nt][r] + b1) * w2;
        }
        float bn2v = bn2[0];
        #pragma unroll
        for (int r = 0; r < 4; ++r) {
            float d = dot[r];
            d += __shfl_xor(d, 1); d += __shfl_xor(d, 2); d += __shfl_xor(d, 4); d += __shfl_xor(d, 8);
            rowadd[r] = lrelu(d + bn2v);
        }
    }

    // ---- residual + LN3 over flat 1024 per token -> stage xu in R0 ----
    {
        float vals[4][4];
        float s = 0.0f, sq = 0.0f;
        #pragma unroll
        for (int nt = 0; nt < 4; ++nt)
            #pragma unroll
            for (int r = 0; r < 4; ++r) {
                float v = xfnv[nt][r] + rowadd[r];
                vals[nt][r] = v;
                s += v; sq += v * v;
            }
        s += __shfl_xor(s, 1); s += __shfl_xor(s, 2); s += __shfl_xor(s, 4);
        s += __shfl_xor(s, 8); s += __shfl_xor(s, 16); s += __shfl_xor(s, 32);
        sq += __shfl_xor(sq, 1); sq += __shfl_xor(sq, 2); sq += __shfl_xor(sq, 4);
        sq += __shfl_xor(sq, 8); sq += __shfl_xor(sq, 16); sq += __shfl_xor(sq, 32);
        float m = s * (1.0f / 1024.0f);
        float var = sq * (1.0f / 1024.0f) - m * m;
        float inv = 1.0f / sqrtf(var + 1e-5f);
        #pragma unroll
        for (int nt = 0; nt < 4; ++nt)
            #pragma unroll
            for (int r = 0; r < 4; ++r) {
                int o = (G * 4 + r) * 64 + nt * 16 + li;
                float u = (vals[nt][r] - m) * inv * g3[o] + be3[o];
                *reinterpret_cast<unsigned short*>(R0 + (tok * 16 + G * 4 + r) * 128 + (nt * 16 + li) * 2) = f2bf(u);
            }
    }
    __syncthreads();
    // coalesced copy R0 -> xu
    {
        const uint4* sp = reinterpret_cast<const uint4*>(L + tid * 32);
        uint4 a0 = sp[0], a1 = sp[1];
        uint4* dp = reinterpret_cast<uint4*>(reinterpret_cast<char*>(xu) + (size_t)blockIdx.x * 8192 + tid * 32);
        dp[0] = a0; dp[1] = a1;
    }
}

// ---------------- Kernel 5a: transpose + convert Wu1 -> bf16 Wu1t[n][k] ----------------
__global__ __launch_bounds__(256) void k_cvtW(const float* __restrict__ W,
                                              unsigned short* __restrict__ Wt) {
    __shared__ float tile[32][33];
    int tk = blockIdx.x & 31;
    int tn = blockIdx.x >> 5;
    int c = threadIdx.x & 31, r4 = threadIdx.x >> 5;
    #pragma unroll
    for (int p = 0; p < 4; ++p) {
        int r = p * 8 + r4;
        tile[r][c] = W[(size_t)(tk * 32 + r) * GN + tn * 32 + c];
    }
    __syncthreads();
    #pragma unroll
    for (int p = 0; p < 4; ++p) {
        int r = p * 8 + r4;   // n-local
        Wt[(size_t)(tn * 32 + r) * GK + tk * 32 + c] = f2bf(tile[c][r]);
    }
}

// ---------------- Kernel 5b: MFMA GEMM xu@Wu1 fused with bu1+lrelu+Wu2 row-dot ----------------
__global__ __launch_bounds__(256) void k_gemm(const unsigned short* __restrict__ xu,
                                              const unsigned short* __restrict__ Wt,
                                              const float* __restrict__ bu1,
                                              const float* __restrict__ Wu2,
                                              float* __restrict__ partial) {
    int bm = blockIdx.x;          // 0..255
    int bn = blockIdx.y;          // 0..7
    int tid = threadIdx.x;
    int w = tid >> 6, l = tid & 63;
    int wm = w >> 1, wn = w & 1;
    int lr = l & 15, lg = l >> 4;

    __shared__ unsigned short As[BMt * BKt];
    __shared__ unsigned short Bs[BNt * BKt];
    __shared__ float rowpart[2][BMt];

    f32x4 acc[4][4];
    #pragma unroll
    for (int i = 0; i < 4; ++i)
        #pragma unroll
        for (int j = 0; j < 4; ++j)
            acc[i][j] = (f32x4){0.0f, 0.0f, 0.0f, 0.0f};

    char* Ab = reinterpret_cast<char*>(As);
    char* Bb = reinterpret_cast<char*>(Bs);

    for (int k0 = 0; k0 < GK; k0 += BKt) {
        __syncthreads();
        #pragma unroll
        for (int p = 0; p < 4; ++p) {
            int s = p * 256 + tid;
            int r = s >> 3, c8 = s & 7;
            int off = r * 128 + ((c8 * 16) ^ ((r & 7) << 4));
            uint4 va = *reinterpret_cast<const uint4*>(xu + ((size_t)(bm * BMt + r)) * GK + k0 + c8 * 8);
            *reinterpret_cast<uint4*>(Ab + off) = va;
            uint4 vb = *reinterpret_cast<const uint4*>(Wt + ((size_t)(bn * BNt + r)) * GK + k0 + c8 * 8);
            *reinterpret_cast<uint4*>(Bb + off) = vb;
        }
        __syncthreads();
        #pragma unroll
        for (int ks = 0; ks < 2; ++ks) {
            bf16x8 af[4], bfr[4];
            #pragma unroll
            for (int rf = 0; rf < 4; ++rf) {
                int row = wm * 64 + rf * 16 + lr;
                int coff = (ks * 64 + lg * 16) ^ ((row & 7) << 4);
                af[rf] = *reinterpret_cast<const bf16x8*>(Ab + row * 128 + coff);
            }
            #pragma unroll
            for (int nf = 0; nf < 4; ++nf) {
                int rowb = wn * 64 + nf * 16 + lr;
                int coff = (ks * 64 + lg * 16) ^ ((rowb & 7) << 4);
                bfr[nf] = *reinterpret_cast<const bf16x8*>(Bb + rowb * 128 + coff);
            }
            #pragma unroll
            for (int rf = 0; rf < 4; ++rf)
                #pragma unroll
                for (int nf = 0; nf < 4; ++nf)
                    acc[rf][nf] = __builtin_amdgcn_mfma_f32_16x16x32_bf16(af[rf], bfr[nf], acc[rf][nf], 0, 0, 0);
        }
    }

    float b1v[4], w2v[4];
    #pragma unroll
    for (int nf = 0; nf < 4; ++nf) {
        int nn = bn * BNt + wn * 64 + nf * 16 + lr;
        b1v[nf] = bu1[nn];
        w2v[nf] = Wu2[nn];
    }
    float rowsum[4][4];
    #pragma unroll
    for (int rf = 0; rf < 4; ++rf) {
        #pragma unroll
        for (int j = 0; j < 4; ++j) {
            float s = 0.0f;
            #pragma unroll
            for (int nf = 0; nf < 4; ++nf)
                s += lrelu(acc[rf][nf][j] + b1v[nf]) * w2v[nf];
            #pragma unroll
            for (int off = 1; off < 16; off <<= 1)
                s += __shfl_xor(s, off);
            rowsum[rf][j] = s;
        }
    }
    if (lr == 0) {
        #pragma unroll
        for (int rf = 0; rf < 4; ++rf)
            #pragma unroll
            for (int j = 0; j < 4; ++j)
                rowpart[wn][wm * 64 + rf * 16 + lg * 4 + j] = rowsum[rf][j];
    }
    __syncthreads();
    if (tid < BMt) {
        float v = rowpart[0][tid] + rowpart[1][tid];
        partial[((size_t)(bm * BMt + tid)) * NCHUNK + bn] = v;
    }
}

// ---------------- Kernel 5c: sum partials + bias + lrelu ----------------
__global__ __launch_bounds__(256) void k_reduce(const float* __restrict__ partial,
                                                const float* __restrict__ bu2,
                                                float* __restrict__ out) {
    int m = blockIdx.x * 256 + threadIdx.x;
    float s = bu2[0];
    #pragma unroll
    for (int c = 0; c < NCHUNK; ++c) s += partial[(size_t)m * NCHUNK + c];
    out[m] = lrelu(s);
}

extern "C" void kernel_launch(void* const* d_in, const int* in_sizes, int n_in,
                              void* d_out, int out_size, void* d_ws, size_t ws_size,
                              hipStream_t stream) {
    const float* x   = (const float*)d_in[0];
    const float* c1  = (const float*)d_in[1];
    const float* c2  = (const float*)d_in[2];
    const float* g1  = (const float*)d_in[3];
    const float* be1 = (const float*)d_in[4];
    const float* Wq  = (const float*)d_in[5];
    const float* bq  = (const float*)d_in[6];
    const float* Wk  = (const float*)d_in[7];
    const float* bk  = (const float*)d_in[8];
    const float* Wv  = (const float*)d_in[9];
    const float* bv  = (const float*)d_in[10];
    const float* ls  = (const float*)d_in[11];
    const float* Wo  = (const float*)d_in[12];
    const float* bo  = (const float*)d_in[13];
    const float* Wp1 = (const float*)d_in[14];
    const float* bp1 = (const float*)d_in[15];
    const float* Wp2 = (const float*)d_in[16];
    const float* bp2 = (const float*)d_in[17];
    const float* g2  = (const float*)d_in[18];
    const float* be2 = (const float*)d_in[19];
    const float* Wn1 = (const float*)d_in[20];
    const float* bn1 = (const float*)d_in[21];
    const float* Wn2 = (const float*)d_in[22];
    const float* bn2 = (const float*)d_in[23];
    const float* g3  = (const float*)d_in[24];
    const float* be3 = (const float*)d_in[25];
    const float* Wu1 = (const float*)d_in[26];
    const float* bu1 = (const float*)d_in[27];
    const float* Wu2 = (const float*)d_in[28];
    const float* bu2 = (const float*)d_in[29];
    float* out = (float*)d_out;

    char* ws = (char*)d_ws;
    size_t off = 0;
    int*   idx  = (int*)(ws + off);   off += (size_t)TT * NHH * 4;
    float* c1n  = (float*)(ws + off); off += (size_t)TT * NHH * 4;
    float* c2n  = (float*)(ws + off); off += (size_t)TT * NHH * 4;
    float* bias = (float*)(ws + off); off += (size_t)TT * HEADSS * NHH * NHH * 4;   // 16 MB
    unsigned short* xnb  = (unsigned short*)(ws + off); off += (size_t)BB * TT * MDD * 2;   // 4 MB
    unsigned short* xuB  = (unsigned short*)(ws + off); off += (size_t)GM * GK * 2;         // 64 MB
    unsigned short* Wu1t = (unsigned short*)(ws + off); off += (size_t)GK * GN * 2;         // 2 MB
    float* partial = (float*)(ws + off); off += (size_t)GM * NCHUNK * 4;                    // 1 MB
    unsigned short* Wqkvt = (unsigned short*)(ws + off); off += 192 * 64 * 2;
    unsigned short* Wot   = (unsigned short*)(ws + off); off += 64 * 64 * 2;
    unsigned short* Wn1t  = (unsigned short*)(ws + off); off += 256 * 64 * 2;

    k_neighbors<<<TT, 256, 0, stream>>>(c1, c2, idx, c1n, c2n);
    k_bias<<<(TT * NHH * NHH + 255) / 256, 256, 0, stream>>>(c1n, c2n, Wp1, bp1, Wp2, bp2, bias);
    k_ln1<<<(BB * TT) / 4, 256, 0, stream>>>(x, g1, be1, xnb);
    k_prepw<<<128, 256, 0, stream>>>(Wq, Wk, Wv, Wo, Wn1, Wqkvt, Wot, Wn1t);
    k_cvtW<<<1024, 256, 0, stream>>>(Wu1, Wu1t);
    k_main<<<(BB * TT) / 4, 256, 0, stream>>>(xnb, idx, bias, Wqkvt, Wot, Wn1t,
                                              bq, bk, bv, ls, bo, g2, be2, bn1, Wn2, bn2, g3, be3, xuB);
    k_gemm<<<dim3(GM / BMt, GN / BNt), 256, 0, stream>>>(xuB, Wu1t, bu1, Wu2, partial);
    k_reduce<<<GM / 256, 256, 0, stream>>>(partial, bu2, out);
}